// Round 1
// baseline (153.534 us; speedup 1.0000x reference)
//
#include <hip/hip_runtime.h>

// BaseModel_3100966387783: per-variable masked 3-layer MLP
//   b=8192 batch, D=128 variables, h=64 hidden, o=2 out
//   layer0: h[b,t,i] = leaky( sum_{j!=t} w0[t,i,j] x[b,j] + b0[t,i] )
//   layer1: h2 = leaky( w1[t] @ h + b1[t] )
//   layer2: out[b,t,i] = w2[t] @ h2 + b2[t]        (out: (8192,128,2) fp32)
//
// Strategy: fused bf16-MFMA kernel. One block = (variable t, 128-row batch
// tile). All weights/activations staged in LDS; 16x16x32 bf16 MFMA for all
// three layers (layer2 via zero-padded 16-row B operand). fp32 accumulate,
// fp32 biases. Each wave owns 32 batch rows -> the C-layout -> A-layout
// LDS round-trips between layers are wave-local.

typedef __bf16 bf16_t;
typedef __bf16 bf16x8 __attribute__((ext_vector_type(8)));
typedef float f32x4 __attribute__((ext_vector_type(4)));

#define LEAKY 0.01f

// ---- LDS layout (bytes) ----
// [0, 36864): x tile, 128 rows x 144 bf16 (pitch 144 -> 16B aligned, +8 pad)
//   after layer0 mfma (barrier): reused as
//     h  : 128 rows x 72 bf16 @ byte 0      (18432 B)
//     h2 : 128 rows x 72 bf16 @ byte 18432  (18432 B)
#define W0_OFF 36864                 // w0[t]: 64 x 136 bf16 = 17408 B
#define W1_OFF (W0_OFF + 17408)      // w1[t]: 64 x 72 bf16  = 9216 B
#define W2_OFF (W1_OFF + 9216)       // w2[t] padded: 16 x 72 bf16 = 2304 B
#define B0_OFF (W2_OFF + 2304)       // 64 f32
#define B1_OFF (B0_OFF + 256)        // 64 f32
#define B2_OFF (B1_OFF + 256)        // 2 f32
#define SMEM_BYTES (B2_OFF + 16)     // 66336 B -> 2 blocks/CU

__global__ __launch_bounds__(256, 2)
void fused_mlp_kernel(const float* __restrict__ x,
                      const float* __restrict__ w0,
                      const float* __restrict__ w1,
                      const float* __restrict__ w2,
                      const float* __restrict__ b0,
                      const float* __restrict__ b1,
                      const float* __restrict__ b2,
                      float* __restrict__ out)
{
    __shared__ __align__(16) unsigned char smem[SMEM_BYTES];
    bf16_t* bufX  = (bf16_t*)smem;            // pitch 144 (x tile)
    bf16_t* bufH  = (bf16_t*)smem;            // pitch 72  (after barrier)
    bf16_t* bufH2 = (bf16_t*)(smem + 18432);  // pitch 72
    bf16_t* w0s   = (bf16_t*)(smem + W0_OFF); // pitch 136
    bf16_t* w1s   = (bf16_t*)(smem + W1_OFF); // pitch 72
    bf16_t* w2s   = (bf16_t*)(smem + W2_OFF); // pitch 72, 16 rows (2 real)
    float*  b0s   = (float*)(smem + B0_OFF);
    float*  b1s   = (float*)(smem + B1_OFF);
    float*  b2s   = (float*)(smem + B2_OFF);

    const int tid     = threadIdx.x;
    const int t       = blockIdx.y;      // variable index 0..127
    const int rowBase = blockIdx.x * 128; // batch-tile start

    // ---------------- stage x tile: 128x128 fp32 -> bf16 LDS ----------------
    #pragma unroll
    for (int it = 0; it < 16; ++it) {
        int e = tid * 4 + it * 1024;           // 0..16383
        int r = e >> 7, c = e & 127;
        const float4 v = *(const float4*)(x + (size_t)(rowBase + r) * 128 + c);
        bf16_t* dst = bufX + r * 144 + c;
        dst[0] = (bf16_t)v.x; dst[1] = (bf16_t)v.y;
        dst[2] = (bf16_t)v.z; dst[3] = (bf16_t)v.w;
    }
    // ---------------- stage w0[t] with mask (col j == t -> 0) ---------------
    const float* w0t = w0 + (size_t)t * (64 * 128);
    #pragma unroll
    for (int it = 0; it < 8; ++it) {
        int e = tid * 4 + it * 1024;           // 0..8191
        int i = e >> 7, j = e & 127;
        float4 v = *(const float4*)(w0t + e);
        if (j     == t) v.x = 0.f;
        if (j + 1 == t) v.y = 0.f;
        if (j + 2 == t) v.z = 0.f;
        if (j + 3 == t) v.w = 0.f;
        bf16_t* dst = w0s + i * 136 + j;
        dst[0] = (bf16_t)v.x; dst[1] = (bf16_t)v.y;
        dst[2] = (bf16_t)v.z; dst[3] = (bf16_t)v.w;
    }
    // ---------------- stage w1[t] ----------------
    const float* w1t = w1 + (size_t)t * (64 * 64);
    #pragma unroll
    for (int it = 0; it < 4; ++it) {
        int e = tid * 4 + it * 1024;           // 0..4095
        int i = e >> 6, j = e & 63;
        const float4 v = *(const float4*)(w1t + e);
        bf16_t* dst = w1s + i * 72 + j;
        dst[0] = (bf16_t)v.x; dst[1] = (bf16_t)v.y;
        dst[2] = (bf16_t)v.z; dst[3] = (bf16_t)v.w;
    }
    // ---------------- stage w2[t] zero-padded to 16 rows ----------------
    for (int s = tid; s < 16 * 72; s += 256) {
        int i = s / 72, j = s - i * 72;
        float v = (i < 2 && j < 64) ? w2[(size_t)t * 128 + i * 64 + j] : 0.f;
        w2s[s] = (bf16_t)v;
    }
    // ---------------- biases (fp32) ----------------
    if (tid < 64)        b0s[tid]       = b0[(size_t)t * 64 + tid];
    else if (tid < 128)  b1s[tid - 64]  = b1[(size_t)t * 64 + (tid - 64)];
    else if (tid < 130)  b2s[tid - 128] = b2[(size_t)t * 2 + (tid - 128)];

    __syncthreads();   // B1: staging complete

    const int wave = tid >> 6;
    const int lane = tid & 63;
    const int lr   = lane & 15;   // A row-in-tile / B col(n) / C col
    const int lk   = lane >> 4;   // k-group / C row-group

    const f32x4 zero = {0.f, 0.f, 0.f, 0.f};

    // =============== layer 0: [128x128] @ w0[t]^T -> [128x64] ===============
    f32x4 acc[2][4];
    #pragma unroll
    for (int mt = 0; mt < 2; ++mt)
        #pragma unroll
        for (int nt = 0; nt < 4; ++nt) acc[mt][nt] = zero;

    #pragma unroll
    for (int ks = 0; ks < 4; ++ks) {
        int k0 = ks * 32 + lk * 8;
        bf16x8 a0 = *(const bf16x8*)(bufX + ((wave * 2 + 0) * 16 + lr) * 144 + k0);
        bf16x8 a1 = *(const bf16x8*)(bufX + ((wave * 2 + 1) * 16 + lr) * 144 + k0);
        #pragma unroll
        for (int nt = 0; nt < 4; ++nt) {
            bf16x8 bf = *(const bf16x8*)(w0s + (nt * 16 + lr) * 136 + k0);
            acc[0][nt] = __builtin_amdgcn_mfma_f32_16x16x32_bf16(a0, bf, acc[0][nt], 0, 0, 0);
            acc[1][nt] = __builtin_amdgcn_mfma_f32_16x16x32_bf16(a1, bf, acc[1][nt], 0, 0, 0);
        }
    }
    __syncthreads();   // B2: everyone done reading bufX -> safe to overwrite

    // epilogue 0: bias + leaky, fp32 -> bf16, C-layout -> row-major bufH
    #pragma unroll
    for (int mt = 0; mt < 2; ++mt)
        #pragma unroll
        for (int nt = 0; nt < 4; ++nt)
            #pragma unroll
            for (int r = 0; r < 4; ++r) {
                int row = (wave * 2 + mt) * 16 + lk * 4 + r;
                int col = nt * 16 + lr;
                float v = acc[mt][nt][r] + b0s[col];
                v = v > 0.f ? v : LEAKY * v;
                bufH[row * 72 + col] = (bf16_t)v;
            }
    __syncthreads();   // B3: h visible

    // =============== layer 1: [128x64] @ w1[t]^T -> [128x64] ===============
    f32x4 acc1[2][4];
    #pragma unroll
    for (int mt = 0; mt < 2; ++mt)
        #pragma unroll
        for (int nt = 0; nt < 4; ++nt) acc1[mt][nt] = zero;

    #pragma unroll
    for (int ks = 0; ks < 2; ++ks) {
        int k0 = ks * 32 + lk * 8;
        bf16x8 a0 = *(const bf16x8*)(bufH + ((wave * 2 + 0) * 16 + lr) * 72 + k0);
        bf16x8 a1 = *(const bf16x8*)(bufH + ((wave * 2 + 1) * 16 + lr) * 72 + k0);
        #pragma unroll
        for (int nt = 0; nt < 4; ++nt) {
            bf16x8 bf = *(const bf16x8*)(w1s + (nt * 16 + lr) * 72 + k0);
            acc1[0][nt] = __builtin_amdgcn_mfma_f32_16x16x32_bf16(a0, bf, acc1[0][nt], 0, 0, 0);
            acc1[1][nt] = __builtin_amdgcn_mfma_f32_16x16x32_bf16(a1, bf, acc1[1][nt], 0, 0, 0);
        }
    }

    // epilogue 1: bias + leaky -> bf16 bufH2 (disjoint from bufH)
    #pragma unroll
    for (int mt = 0; mt < 2; ++mt)
        #pragma unroll
        for (int nt = 0; nt < 4; ++nt)
            #pragma unroll
            for (int r = 0; r < 4; ++r) {
                int row = (wave * 2 + mt) * 16 + lk * 4 + r;
                int col = nt * 16 + lr;
                float v = acc1[mt][nt][r] + b1s[col];
                v = v > 0.f ? v : LEAKY * v;
                bufH2[row * 72 + col] = (bf16_t)v;
            }
    __syncthreads();   // B4: h2 visible

    // =============== layer 2: [128x64] @ w2[t]^T(pad16) -> [128x2] ==========
    f32x4 acc2[2];
    acc2[0] = zero; acc2[1] = zero;
    #pragma unroll
    for (int ks = 0; ks < 2; ++ks) {
        int k0 = ks * 32 + lk * 8;
        bf16x8 a0 = *(const bf16x8*)(bufH2 + ((wave * 2 + 0) * 16 + lr) * 72 + k0);
        bf16x8 a1 = *(const bf16x8*)(bufH2 + ((wave * 2 + 1) * 16 + lr) * 72 + k0);
        bf16x8 bf = *(const bf16x8*)(w2s + lr * 72 + k0);
        acc2[0] = __builtin_amdgcn_mfma_f32_16x16x32_bf16(a0, bf, acc2[0], 0, 0, 0);
        acc2[1] = __builtin_amdgcn_mfma_f32_16x16x32_bf16(a1, bf, acc2[1], 0, 0, 0);
    }

    // epilogue 2: only output cols 0,1 are real; out[b, t, i], fp32
    if (lr < 2) {
        #pragma unroll
        for (int mt = 0; mt < 2; ++mt)
            #pragma unroll
            for (int r = 0; r < 4; ++r) {
                int row = rowBase + (wave * 2 + mt) * 16 + lk * 4 + r;
                out[(size_t)row * 256 + t * 2 + lr] = acc2[mt][r] + b2s[lr];
            }
    }
}

extern "C" void kernel_launch(void* const* d_in, const int* in_sizes, int n_in,
                              void* d_out, int out_size, void* d_ws, size_t ws_size,
                              hipStream_t stream) {
    const float* x  = (const float*)d_in[0];
    const float* w0 = (const float*)d_in[1];
    const float* w1 = (const float*)d_in[2];
    const float* w2 = (const float*)d_in[3];
    const float* b0 = (const float*)d_in[4];
    const float* b1 = (const float*)d_in[5];
    const float* b2 = (const float*)d_in[6];
    float* out = (float*)d_out;

    dim3 grid(64, 128, 1);   // x: batch tiles (fast-varying, shares t in L2)
    dim3 block(256, 1, 1);
    fused_mlp_kernel<<<grid, block, 0, stream>>>(x, w0, w1, w2, b0, b1, b2, out);
}

// Round 2
// 123.640 us; speedup vs baseline: 1.2418x; 1.2418x over previous
//
#include <hip/hip_runtime.h>

// BaseModel_3100966387783 — per-variable masked 3-layer MLP, b=8192, D=128, h=64, o=2.
//
// R2 design: "brick" layout. A brick = 1 KB = 64 lanes x 16 B bf16; lane l holds
//   T[row = tile*16 + (l&15)][k = ks*32 + (l>>4)*8 + 0..7]
// which is simultaneously (a) the exact MFMA A/B fragment load (ds_read_b128 /
// global_load_dwordx4 at base + lane*16, conflict-free), and (b) the exact
// global_load_lds DMA order (wave-uniform base + lane*16).
//
// Pre-kernel converts fp32 -> bf16 once into bricks in d_ws (w0 pre-masked
// col j==t -> 0, w2 zero-padded to 16 rows). Main kernel computes all layers
// TRANSPOSED (D = W * X^T), so each C-fragment's 4 regs are 4 consecutive k of
// the next layer's B operand -> epilogue = one ds_write_b64 straight into the
// next layer's brick. No barriers after staging (h bricks are wave-private).

typedef __bf16 bf16_t;
typedef __bf16 bf16x8 __attribute__((ext_vector_type(8)));
typedef float  f32x4  __attribute__((ext_vector_type(4)));

#define LEAKY 0.01f

// ---------------- ws brick regions (byte offsets) ----------------
#define XB_OFF   0u                  // x bricks:   64 bt x 8 nt x 4 ks = 2048 bricks
#define W0B_OFF  (2048u*1024u)       // w0 masked: 128 t x 4 it x 4 ks = 2048
#define W1B_OFF  (4096u*1024u)       // w1:        128 t x 4 it x 2 ks = 1024
#define W2B_OFF  (5120u*1024u)       // w2 pad16:  128 t x 2 ks        =  256
// total ws need: 5376 KiB

// ---------------- main-kernel LDS layout (bytes) ----------------
#define W0L   0        // 16 bricks (it*4+ks)
#define W1L   16384    //  8 bricks (it*2+ks1)
#define W2L   24576    //  2 bricks (ks2)
#define HL    26624    // h  bricks: 8 nt x 2 ks1 = 16 KB
#define H2L   43008    // h2 bricks: 8 nt x 2 ks2 = 16 KB
#define SMEMB 59392    // 2 blocks/CU

__device__ __forceinline__ void async_copy16(void* lds, const void* g) {
    __builtin_amdgcn_global_load_lds(
        (const __attribute__((address_space(1))) unsigned int*)g,
        (__attribute__((address_space(3))) unsigned int*)lds, 16, 0, 0);
}

// =================== pre-kernel: fp32 -> bf16 brick-ify ===================
__global__ __launch_bounds__(256)
void brickify(const float* __restrict__ x,  const float* __restrict__ w0,
              const float* __restrict__ w1, const float* __restrict__ w2,
              unsigned char* __restrict__ ws)
{
    const int wid  = blockIdx.x * 4 + (threadIdx.x >> 6);  // one wave = one brick
    const int lane = threadIdx.x & 63;
    const int lr = lane & 15, lq = lane >> 4;

    float v[8];
    if (wid < 2048) {                        // ---- x bricks ----
        int bt = wid >> 5, rem = wid & 31, nt = rem >> 2, ks = rem & 3;
        const float* s = x + (size_t)(bt*128 + nt*16 + lr) * 128 + ks*32 + lq*8;
        const float4 a = *(const float4*)s, b = *(const float4*)(s + 4);
        v[0]=a.x; v[1]=a.y; v[2]=a.z; v[3]=a.w;
        v[4]=b.x; v[5]=b.y; v[6]=b.z; v[7]=b.w;
    } else if (wid < 4096) {                 // ---- w0 bricks (masked) ----
        int u = wid - 2048, t = u >> 4, rem = u & 15, it = rem >> 2, ks = rem & 3;
        int k0 = ks*32 + lq*8;
        const float* s = w0 + (size_t)(t*64 + it*16 + lr) * 128 + k0;
        const float4 a = *(const float4*)s, b = *(const float4*)(s + 4);
        v[0]=a.x; v[1]=a.y; v[2]=a.z; v[3]=a.w;
        v[4]=b.x; v[5]=b.y; v[6]=b.z; v[7]=b.w;
        #pragma unroll
        for (int j = 0; j < 8; ++j) if (k0 + j == t) v[j] = 0.f;
    } else if (wid < 5120) {                 // ---- w1 bricks ----
        int u = wid - 4096, t = u >> 3, rem = u & 7, it = rem >> 1, ks = rem & 1;
        const float* s = w1 + (size_t)(t*64 + it*16 + lr) * 64 + ks*32 + lq*8;
        const float4 a = *(const float4*)s, b = *(const float4*)(s + 4);
        v[0]=a.x; v[1]=a.y; v[2]=a.z; v[3]=a.w;
        v[4]=b.x; v[5]=b.y; v[6]=b.z; v[7]=b.w;
    } else {                                 // ---- w2 bricks, rows>=2 zero ----
        int u = wid - 5120, t = u >> 1, ks = u & 1;
        #pragma unroll
        for (int j = 0; j < 8; ++j) v[j] = 0.f;
        if (lr < 2) {
            const float* s = w2 + (size_t)(t*2 + lr) * 64 + ks*32 + lq*8;
            const float4 a = *(const float4*)s, b = *(const float4*)(s + 4);
            v[0]=a.x; v[1]=a.y; v[2]=a.z; v[3]=a.w;
            v[4]=b.x; v[5]=b.y; v[6]=b.z; v[7]=b.w;
        }
    }
    union { bf16_t h[8]; uint4 q; } pk;
    #pragma unroll
    for (int j = 0; j < 8; ++j) pk.h[j] = (bf16_t)v[j];
    ((uint4*)ws)[(size_t)wid * 64 + lane] = pk.q;   // dst = brick*1024 + lane*16
}

// =========================== main fused kernel ===========================
__global__ __launch_bounds__(256, 2)
void fused_mlp(const unsigned char* __restrict__ ws,
               const float* __restrict__ b0, const float* __restrict__ b1,
               const float* __restrict__ b2, float* __restrict__ out)
{
    __shared__ __align__(1024) unsigned char smem[SMEMB];
    const int tid  = threadIdx.x;
    const int w    = tid >> 6;         // wave 0..3: owns rows w*32 .. w*32+31
    const int lane = tid & 63;
    const int lr = lane & 15, lq = lane >> 4;
    const int bt = blockIdx.x;         // batch tile (fast dim -> weights[t] hot in L2)
    const int t  = blockIdx.y;

    // ---- x fragments: straight global -> VGPR from bricks (no LDS) ----
    bf16x8 xf[2][4];
    #pragma unroll
    for (int ntl = 0; ntl < 2; ++ntl) {
        int ntg = w * 2 + ntl;
        #pragma unroll
        for (int ks = 0; ks < 4; ++ks)
            xf[ntl][ks] = *(const bf16x8*)(ws + XB_OFF
                            + (size_t)(((bt*8 + ntg)*4 + ks) * 1024) + lane*16);
    }
    // ---- biases into registers (per-quad float4) ----
    f32x4 b0q[4], b1q[4];
    #pragma unroll
    for (int it = 0; it < 4; ++it) {
        b0q[it] = *(const f32x4*)(b0 + t*64 + it*16 + lq*4);
        b1q[it] = *(const f32x4*)(b1 + t*64 + it*16 + lq*4);
    }
    const float2 b2v = *(const float2*)(b2 + t*2);

    // ---- weights: global_load_lds DMA, 26 x 1KB chunks ----
    for (int c = w; c < 26; c += 4) {
        const unsigned char* g;
        if (c < 16)      g = ws + W0B_OFF + (size_t)t*16384 + c*1024;
        else if (c < 24) g = ws + W1B_OFF + (size_t)t*8192  + (c-16)*1024;
        else             g = ws + W2B_OFF + (size_t)t*2048  + (c-24)*1024;
        async_copy16(smem + c*1024 + lane*16, g + lane*16);
    }
    __syncthreads();   // the only barrier: drain DMA, weights visible

    // =================== layer 0: D0[i][row] = w0m @ x^T ===================
    bf16x8 w0f[4][4];
    #pragma unroll
    for (int it = 0; it < 4; ++it)
        #pragma unroll
        for (int ks = 0; ks < 4; ++ks)
            w0f[it][ks] = *(const bf16x8*)(smem + W0L + (it*4+ks)*1024 + lane*16);

    f32x4 acc0[2][4];
    #pragma unroll
    for (int a = 0; a < 2; ++a)
        #pragma unroll
        for (int b = 0; b < 4; ++b) acc0[a][b] = (f32x4){0.f,0.f,0.f,0.f};

    #pragma unroll
    for (int ks = 0; ks < 4; ++ks)
        #pragma unroll
        for (int it = 0; it < 4; ++it)
            #pragma unroll
            for (int ntl = 0; ntl < 2; ++ntl)
                acc0[ntl][it] = __builtin_amdgcn_mfma_f32_16x16x32_bf16(
                                    w0f[it][ks], xf[ntl][ks], acc0[ntl][it], 0, 0, 0);

    // epilogue 0 -> h bricks: C-frag reg r is k = it*16 + lq*4 + r (4 consecutive k)
    #pragma unroll
    for (int ntl = 0; ntl < 2; ++ntl)
        #pragma unroll
        for (int it = 0; it < 4; ++it) {
            union { bf16_t h[4]; unsigned long long u; } pk;
            #pragma unroll
            for (int r = 0; r < 4; ++r) {
                float u = acc0[ntl][it][r] + b0q[it][r];
                pk.h[r] = (bf16_t)(u > 0.f ? u : LEAKY * u);
            }
            int off = ((w*2+ntl)*2 + (it>>1)) * 1024
                    + (((it&1)*2 + (lq>>1))*16 + lr) * 16 + (lq&1)*8;
            *(unsigned long long*)(smem + HL + off) = pk.u;
        }

    // =================== layer 1: D1[i2][row] = w1 @ h^T ===================
    bf16x8 w1f[4][2], hf[2][2];
    #pragma unroll
    for (int it = 0; it < 4; ++it)
        #pragma unroll
        for (int ks = 0; ks < 2; ++ks)
            w1f[it][ks] = *(const bf16x8*)(smem + W1L + (it*2+ks)*1024 + lane*16);
    #pragma unroll
    for (int ntl = 0; ntl < 2; ++ntl)
        #pragma unroll
        for (int ks = 0; ks < 2; ++ks)
            hf[ntl][ks] = *(const bf16x8*)(smem + HL + ((w*2+ntl)*2 + ks)*1024 + lane*16);

    f32x4 acc1[2][4];
    #pragma unroll
    for (int a = 0; a < 2; ++a)
        #pragma unroll
        for (int b = 0; b < 4; ++b) acc1[a][b] = (f32x4){0.f,0.f,0.f,0.f};

    #pragma unroll
    for (int ks = 0; ks < 2; ++ks)
        #pragma unroll
        for (int it = 0; it < 4; ++it)
            #pragma unroll
            for (int ntl = 0; ntl < 2; ++ntl)
                acc1[ntl][it] = __builtin_amdgcn_mfma_f32_16x16x32_bf16(
                                    w1f[it][ks], hf[ntl][ks], acc1[ntl][it], 0, 0, 0);

    // epilogue 1 -> h2 bricks
    #pragma unroll
    for (int ntl = 0; ntl < 2; ++ntl)
        #pragma unroll
        for (int it = 0; it < 4; ++it) {
            union { bf16_t h[4]; unsigned long long u; } pk;
            #pragma unroll
            for (int r = 0; r < 4; ++r) {
                float u = acc1[ntl][it][r] + b1q[it][r];
                pk.h[r] = (bf16_t)(u > 0.f ? u : LEAKY * u);
            }
            int off = ((w*2+ntl)*2 + (it>>1)) * 1024
                    + (((it&1)*2 + (lq>>1))*16 + lr) * 16 + (lq&1)*8;
            *(unsigned long long*)(smem + H2L + off) = pk.u;
        }

    // =================== layer 2: D2[o][row] = w2pad @ h2^T ===================
    bf16x8 w2f[2], h2f[2][2];
    #pragma unroll
    for (int ks = 0; ks < 2; ++ks)
        w2f[ks] = *(const bf16x8*)(smem + W2L + ks*1024 + lane*16);
    #pragma unroll
    for (int ntl = 0; ntl < 2; ++ntl)
        #pragma unroll
        for (int ks = 0; ks < 2; ++ks)
            h2f[ntl][ks] = *(const bf16x8*)(smem + H2L + ((w*2+ntl)*2 + ks)*1024 + lane*16);

    f32x4 acc2[2];
    acc2[0] = (f32x4){0.f,0.f,0.f,0.f};
    acc2[1] = (f32x4){0.f,0.f,0.f,0.f};
    #pragma unroll
    for (int ks = 0; ks < 2; ++ks)
        #pragma unroll
        for (int ntl = 0; ntl < 2; ++ntl)
            acc2[ntl] = __builtin_amdgcn_mfma_f32_16x16x32_bf16(
                            w2f[ks], h2f[ntl][ks], acc2[ntl], 0, 0, 0);

    // epilogue 2: only o=0,1 (quad 0, regs 0,1) are real -> 8B store per row
    if (lq == 0) {
        #pragma unroll
        for (int ntl = 0; ntl < 2; ++ntl) {
            int row = bt*128 + (w*2+ntl)*16 + lr;
            float2 o2 = { acc2[ntl][0] + b2v.x, acc2[ntl][1] + b2v.y };
            *(float2*)(out + (size_t)row*256 + t*2) = o2;
        }
    }
}

extern "C" void kernel_launch(void* const* d_in, const int* in_sizes, int n_in,
                              void* d_out, int out_size, void* d_ws, size_t ws_size,
                              hipStream_t stream) {
    const float* x  = (const float*)d_in[0];
    const float* w0 = (const float*)d_in[1];
    const float* w1 = (const float*)d_in[2];
    const float* w2 = (const float*)d_in[3];
    const float* b0 = (const float*)d_in[4];
    const float* b1 = (const float*)d_in[5];
    const float* b2 = (const float*)d_in[6];
    unsigned char* ws = (unsigned char*)d_ws;   // needs 5376 KiB
    float* out = (float*)d_out;

    // 5376 bricks, one wave each, 4 waves/block
    brickify<<<dim3(1344), dim3(256), 0, stream>>>(x, w0, w1, w2, ws);
    fused_mlp<<<dim3(64, 128), dim3(256), 0, stream>>>(ws, b0, b1, b2, out);
}

// Round 3
// 107.441 us; speedup vs baseline: 1.4290x; 1.1508x over previous
//
#include <hip/hip_runtime.h>

// BaseModel_3100966387783 — per-variable masked 3-layer MLP, b=8192, D=128, h=64, o=2.
//
// R3: brick layout (see R2) + register-resident weights + persistent bt-loop.
//   brick = 1 KB = 64 lanes x 16 B bf16; lane l holds T[tile*16 + (l&15)][ks*32 + (l>>4)*8 + 0..7]
//   = exactly one MFMA A/B fragment (load at base + lane*16, coalesced/conflict-free).
//
// brickify: fp32 -> bf16 bricks in d_ws (w0 pre-masked j==t -> 0, w2 zero-padded).
// fused_mlp: one block = (variable t, batch-group of 8 x 128-row tiles).
//   - all weight fragments global->VGPR once (104 regs), L2-resident
//   - loop 8 batch tiles: L0 -> wave-private LDS h bricks -> L1 -> (overwrite) -> L2
//   - x frags for iter s+1 prefetched into the same regs right after iter s's L0
//   - acc initialized with bias (C-operand trick); leaky = max(v, 0.01v)
//   - ZERO barriers, 16.4 KB LDS, 2 waves/SIMD by VGPR.

typedef __bf16 bf16_t;
typedef __bf16 bf16x8 __attribute__((ext_vector_type(8)));
typedef float  f32x4  __attribute__((ext_vector_type(4)));

#define LEAKY 0.01f

// ---------------- ws brick regions (byte offsets) ----------------
#define XB_OFF   0u                  // x bricks:   64 bt x 8 nt x 4 ks = 2048 bricks
#define W0B_OFF  (2048u*1024u)       // w0 masked: 128 t x 4 it x 4 ks = 2048
#define W1B_OFF  (4096u*1024u)       // w1:        128 t x 4 it x 2 ks = 1024
#define W2B_OFF  (5120u*1024u)       // w2 pad16:  128 t x 2 ks        =  256
// total ws need: 5376 KiB

// =================== pre-kernel: fp32 -> bf16 brick-ify ===================
__global__ __launch_bounds__(256)
void brickify(const float* __restrict__ x,  const float* __restrict__ w0,
              const float* __restrict__ w1, const float* __restrict__ w2,
              unsigned char* __restrict__ ws)
{
    const int wid  = blockIdx.x * 4 + (threadIdx.x >> 6);  // one wave = one brick
    const int lane = threadIdx.x & 63;
    const int lr = lane & 15, lq = lane >> 4;

    float v[8];
    if (wid < 2048) {                        // ---- x bricks ----
        int bt = wid >> 5, rem = wid & 31, nt = rem >> 2, ks = rem & 3;
        const float* s = x + (size_t)(bt*128 + nt*16 + lr) * 128 + ks*32 + lq*8;
        const float4 a = *(const float4*)s, b = *(const float4*)(s + 4);
        v[0]=a.x; v[1]=a.y; v[2]=a.z; v[3]=a.w;
        v[4]=b.x; v[5]=b.y; v[6]=b.z; v[7]=b.w;
    } else if (wid < 4096) {                 // ---- w0 bricks (masked) ----
        int u = wid - 2048, t = u >> 4, rem = u & 15, it = rem >> 2, ks = rem & 3;
        int k0 = ks*32 + lq*8;
        const float* s = w0 + (size_t)(t*64 + it*16 + lr) * 128 + k0;
        const float4 a = *(const float4*)s, b = *(const float4*)(s + 4);
        v[0]=a.x; v[1]=a.y; v[2]=a.z; v[3]=a.w;
        v[4]=b.x; v[5]=b.y; v[6]=b.z; v[7]=b.w;
        #pragma unroll
        for (int j = 0; j < 8; ++j) if (k0 + j == t) v[j] = 0.f;
    } else if (wid < 5120) {                 // ---- w1 bricks ----
        int u = wid - 4096, t = u >> 3, rem = u & 7, it = rem >> 1, ks = rem & 1;
        const float* s = w1 + (size_t)(t*64 + it*16 + lr) * 64 + ks*32 + lq*8;
        const float4 a = *(const float4*)s, b = *(const float4*)(s + 4);
        v[0]=a.x; v[1]=a.y; v[2]=a.z; v[3]=a.w;
        v[4]=b.x; v[5]=b.y; v[6]=b.z; v[7]=b.w;
    } else {                                 // ---- w2 bricks, rows>=2 zero ----
        int u = wid - 5120, t = u >> 1, ks = u & 1;
        #pragma unroll
        for (int j = 0; j < 8; ++j) v[j] = 0.f;
        if (lr < 2) {
            const float* s = w2 + (size_t)(t*2 + lr) * 64 + ks*32 + lq*8;
            const float4 a = *(const float4*)s, b = *(const float4*)(s + 4);
            v[0]=a.x; v[1]=a.y; v[2]=a.z; v[3]=a.w;
            v[4]=b.x; v[5]=b.y; v[6]=b.z; v[7]=b.w;
        }
    }
    union { bf16_t h[8]; uint4 q; } pk;
    #pragma unroll
    for (int j = 0; j < 8; ++j) pk.h[j] = (bf16_t)v[j];
    ((uint4*)ws)[(size_t)wid * 64 + lane] = pk.q;   // dst = brick*1024 + lane*16
}

// =========================== main fused kernel ===========================
__global__ __launch_bounds__(256, 2)
void fused_mlp(const unsigned char* __restrict__ ws,
               const float* __restrict__ b0, const float* __restrict__ b1,
               const float* __restrict__ b2, float* __restrict__ out)
{
    // h bricks only: 8 nt-tiles x 2 ks = 16 bricks, wave-private slices. No barriers.
    __shared__ __align__(16) unsigned char hsm[16384];

    const int tid  = threadIdx.x;
    const int w    = tid >> 6;         // wave 0..3: owns batch rows w*32 .. w*32+31
    const int lane = tid & 63;
    const int lr = lane & 15, lq = lane >> 4;
    const int g  = blockIdx.x;         // batch group: bt = g*8 + s
    const int t  = blockIdx.y;         // variable index

    // ---- weights: global -> registers (L2-hit, coalesced 1 KB/instr) ----
    const unsigned char* w0p = ws + W0B_OFF + (size_t)t*16384 + lane*16;
    const unsigned char* w1p = ws + W1B_OFF + (size_t)t*8192  + lane*16;
    const unsigned char* w2p = ws + W2B_OFF + (size_t)t*2048  + lane*16;
    bf16x8 w0f[4][4], w1f[4][2], w2f[2];
    #pragma unroll
    for (int it = 0; it < 4; ++it)
        #pragma unroll
        for (int ks = 0; ks < 4; ++ks)
            w0f[it][ks] = *(const bf16x8*)(w0p + (it*4+ks)*1024);
    #pragma unroll
    for (int it = 0; it < 4; ++it)
        #pragma unroll
        for (int ks = 0; ks < 2; ++ks)
            w1f[it][ks] = *(const bf16x8*)(w1p + (it*2+ks)*1024);
    #pragma unroll
    for (int ks = 0; ks < 2; ++ks)
        w2f[ks] = *(const bf16x8*)(w2p + ks*1024);

    // ---- biases: per-quad float4 (acc-init form) ----
    f32x4 b0q[4], b1q[4];
    #pragma unroll
    for (int it = 0; it < 4; ++it) {
        b0q[it] = *(const f32x4*)(b0 + t*64 + it*16 + lq*4);
        b1q[it] = *(const f32x4*)(b1 + t*64 + it*16 + lq*4);
    }
    const float2 b2v = *(const float2*)(b2 + t*2);

    // ---- x fragment pointer helper; preload iter 0 ----
    const unsigned char* xp = ws + XB_OFF + lane*16;
    bf16x8 xf[2][4];
    {
        const int bt0 = g*8;
        #pragma unroll
        for (int ntl = 0; ntl < 2; ++ntl)
            #pragma unroll
            for (int ks = 0; ks < 4; ++ks)
                xf[ntl][ks] = *(const bf16x8*)(xp + (size_t)(((bt0*8 + w*2+ntl)*4 + ks))*1024);
    }

    for (int s = 0; s < 8; ++s) {
        const int bt = g*8 + s;

        // ============ layer 0: D0[i][row] = w0m @ x^T (+b0 via C-init) ============
        f32x4 acc0[2][4];
        #pragma unroll
        for (int ntl = 0; ntl < 2; ++ntl)
            #pragma unroll
            for (int it = 0; it < 4; ++it) acc0[ntl][it] = b0q[it];

        #pragma unroll
        for (int ks = 0; ks < 4; ++ks)
            #pragma unroll
            for (int it = 0; it < 4; ++it)
                #pragma unroll
                for (int ntl = 0; ntl < 2; ++ntl)
                    acc0[ntl][it] = __builtin_amdgcn_mfma_f32_16x16x32_bf16(
                                        w0f[it][ks], xf[ntl][ks], acc0[ntl][it], 0, 0, 0);

        // ---- xf now dead: prefetch next iter's fragments into the same regs ----
        {
            const int btn = (s < 7) ? bt + 1 : bt;
            #pragma unroll
            for (int ntl = 0; ntl < 2; ++ntl)
                #pragma unroll
                for (int ks = 0; ks < 4; ++ks)
                    xf[ntl][ks] = *(const bf16x8*)(xp + (size_t)(((btn*8 + w*2+ntl)*4 + ks))*1024);
        }

        // epi0 -> h bricks: C reg r is k = it*16 + lq*4 + r (4 consecutive k) -> one b64
        #pragma unroll
        for (int ntl = 0; ntl < 2; ++ntl)
            #pragma unroll
            for (int it = 0; it < 4; ++it) {
                union { bf16_t h[4]; unsigned long long u; } pk;
                #pragma unroll
                for (int r = 0; r < 4; ++r) {
                    float u = acc0[ntl][it][r];
                    pk.h[r] = (bf16_t)fmaxf(u, LEAKY * u);
                }
                int off = ((w*2+ntl)*2 + (it>>1)) * 1024
                        + (((it&1)*2 + (lq>>1))*16 + lr) * 16 + (lq&1)*8;
                *(unsigned long long*)(hsm + off) = pk.u;
            }

        // ============ layer 1: D1[i2][row] = w1 @ h^T (+b1 via C-init) ============
        bf16x8 hf[2][2];
        #pragma unroll
        for (int ntl = 0; ntl < 2; ++ntl)
            #pragma unroll
            for (int ks = 0; ks < 2; ++ks)
                hf[ntl][ks] = *(const bf16x8*)(hsm + ((w*2+ntl)*2 + ks)*1024 + lane*16);

        f32x4 acc1[2][4];
        #pragma unroll
        for (int ntl = 0; ntl < 2; ++ntl)
            #pragma unroll
            for (int it = 0; it < 4; ++it) acc1[ntl][it] = b1q[it];

        #pragma unroll
        for (int ks = 0; ks < 2; ++ks)
            #pragma unroll
            for (int it = 0; it < 4; ++it)
                #pragma unroll
                for (int ntl = 0; ntl < 2; ++ntl)
                    acc1[ntl][it] = __builtin_amdgcn_mfma_f32_16x16x32_bf16(
                                        w1f[it][ks], hf[ntl][ks], acc1[ntl][it], 0, 0, 0);

        // epi1 -> h2 bricks, overwriting this wave's own h bricks (DS pipe is
        // in-order per wave; reads above already executed)
        #pragma unroll
        for (int ntl = 0; ntl < 2; ++ntl)
            #pragma unroll
            for (int it = 0; it < 4; ++it) {
                union { bf16_t h[4]; unsigned long long u; } pk;
                #pragma unroll
                for (int r = 0; r < 4; ++r) {
                    float u = acc1[ntl][it][r];
                    pk.h[r] = (bf16_t)fmaxf(u, LEAKY * u);
                }
                int off = ((w*2+ntl)*2 + (it>>1)) * 1024
                        + (((it&1)*2 + (lq>>1))*16 + lr) * 16 + (lq&1)*8;
                *(unsigned long long*)(hsm + off) = pk.u;
            }

        // ============ layer 2: D2[o][row] = w2pad @ h2^T ============
        bf16x8 h2f[2][2];
        #pragma unroll
        for (int ntl = 0; ntl < 2; ++ntl)
            #pragma unroll
            for (int ks = 0; ks < 2; ++ks)
                h2f[ntl][ks] = *(const bf16x8*)(hsm + ((w*2+ntl)*2 + ks)*1024 + lane*16);

        f32x4 acc2[2];
        acc2[0] = (f32x4){0.f,0.f,0.f,0.f};
        acc2[1] = (f32x4){0.f,0.f,0.f,0.f};
        #pragma unroll
        for (int ks = 0; ks < 2; ++ks)
            #pragma unroll
            for (int ntl = 0; ntl < 2; ++ntl)
                acc2[ntl] = __builtin_amdgcn_mfma_f32_16x16x32_bf16(
                                w2f[ks], h2f[ntl][ks], acc2[ntl], 0, 0, 0);

        // store: o=0,1 live in quad 0, regs 0,1 -> 8B per batch row
        if (lq == 0) {
            #pragma unroll
            for (int ntl = 0; ntl < 2; ++ntl) {
                int row = bt*128 + (w*2+ntl)*16 + lr;
                float2 o2 = { acc2[ntl][0] + b2v.x, acc2[ntl][1] + b2v.y };
                *(float2*)(out + (size_t)row*256 + t*2) = o2;
            }
        }
    }
}

extern "C" void kernel_launch(void* const* d_in, const int* in_sizes, int n_in,
                              void* d_out, int out_size, void* d_ws, size_t ws_size,
                              hipStream_t stream) {
    const float* x  = (const float*)d_in[0];
    const float* w0 = (const float*)d_in[1];
    const float* w1 = (const float*)d_in[2];
    const float* w2 = (const float*)d_in[3];
    const float* b0 = (const float*)d_in[4];
    const float* b1 = (const float*)d_in[5];
    const float* b2 = (const float*)d_in[6];
    unsigned char* ws = (unsigned char*)d_ws;   // needs 5376 KiB
    float* out = (float*)d_out;

    brickify<<<dim3(1344), dim3(256), 0, stream>>>(x, w0, w1, w2, ws);
    // grid (8 batch-groups, 128 t): 1024 blocks; if XCD = blockid%8, each XCD
    // sees one group's x bricks (256 KB) + all weights (3.3 MB) -> fits 4 MB L2.
    fused_mlp<<<dim3(8, 128), dim3(256), 0, stream>>>(ws, b0, b1, b2, out);
}